// Round 17
// baseline (34.038 us; speedup 1.0000x reference)
//
#include <hip/hip_runtime.h>
#include <math.h>
#include <stdint.h>

// GE2E loss on MI355X — 4-kernel pipeline. No memsets, no fences, no atomics.
// out = sum_k counts[k]*log(sum_j exp(S[j,k])) - sum_i logit_self[i]
// Logits <= w*1+b = 5 -> exp without max-subtraction is safe in fp32.
// K1 (1024 thr, block=class): ballot-gather centroid; writes inv_norm only
//     (bf16 ebf intermediate eliminated in r16: was pure write+reread traffic).
// K2 (512 thr): MFMA GEMM; A reg-staged from fp32 emb (L3-resident after K1) with
//     on-the-fly x inv_norm + bf16 convert, ds_write AFTER compute (T14 split);
//     B via gload_lds from csum_bf. Swizzled LDS layout, conflict-free frag reads.
// K3 (256 blk x 256 thr): per-class colpart reduce, ONE scattered load per thread
//     (all misses concurrent; 4-deep serial chain of the 64-thr version removed).
// K4 (1 blk): sum contribs - selfparts -> out.
// Self logit: u = csum_y - e; dot(e,u)=dot-1; |u|^2 = nsq - 2*dot + 1.
// LESSON (r5/r14): never single-block-reduce the 256KB colpart (~13us on one CU).
// LESSON (r9): no per-block __threadfence/ticket tails (L2 writeback storm).
// LESSON (r8): cooperative grid.sync ~50us each on MI355X — never use.

typedef __attribute__((ext_vector_type(8))) short bf16x8;
typedef __attribute__((ext_vector_type(4))) float f32x4;
struct alignas(16) US8 { unsigned short u[8]; };

__device__ inline float waveReduceSum(float v) {
#pragma unroll
    for (int m = 32; m >= 1; m >>= 1) v += __shfl_xor(v, m, 64);
    return v;
}
__device__ inline unsigned short f2bf(float f) {
    uint32_t u = __float_as_uint(f);
    return (unsigned short)((u + 0x7FFFu + ((u >> 16) & 1u)) >> 16);
}
__device__ inline void gload_lds16(const void* g, void* l) {
    __builtin_amdgcn_global_load_lds(
        (const __attribute__((address_space(1))) uint32_t*)g,
        (__attribute__((address_space(3))) uint32_t*)l, 16, 0, 0);
}

// --- K1: fused normalize + per-class centroid (block per class, 16 waves) ---
__global__ __launch_bounds__(1024) void k_centroid(
        const float* __restrict__ emb, const int* __restrict__ y,
        const float* __restrict__ wptr, float* __restrict__ inv_norm,
        unsigned short* __restrict__ csum_bf, float* __restrict__ normsq,
        float* __restrict__ colscale, int* __restrict__ counts, int N) {
    __shared__ float part[16][512];
    __shared__ float red[512];
    __shared__ int cnts[16];
    int c = blockIdx.x;
    int tid = threadIdx.x, l = tid & 63, w = tid >> 6;
    int chunk = N >> 4;                       // rows per wave (1024)
    float facc[8] = {0.f, 0.f, 0.f, 0.f, 0.f, 0.f, 0.f, 0.f};
    int cnt = 0;
    int iend = (w + 1) * chunk;
    int i0 = w * chunk;
    int4 y4 = *reinterpret_cast<const int4*>(y + i0 + l * 4);
    for (; i0 < iend; i0 += 256) {
        int4 cy = y4;
        if (i0 + 256 < iend)                  // prefetch next y tile
            y4 = *reinterpret_cast<const int4*>(y + i0 + 256 + l * 4);
#pragma unroll
        for (int comp = 0; comp < 4; ++comp) {
            int yv = (comp == 0) ? cy.x : (comp == 1) ? cy.y : (comp == 2) ? cy.z : cy.w;
            unsigned long long m = __ballot(yv == c);
            cnt += (int)__popcll(m);
            while (m) {                        // wave-uniform mask
                int b = __builtin_ctzll(m);
                m &= m - 1;
                int r = i0 + 4 * b + comp;
                const float4* pr = reinterpret_cast<const float4*>(emb + (size_t)r * 512);
                float4 v0 = pr[l * 2], v1 = pr[l * 2 + 1];
                float s = v0.x * v0.x + v0.y * v0.y + v0.z * v0.z + v0.w * v0.w
                        + v1.x * v1.x + v1.y * v1.y + v1.z * v1.z + v1.w * v1.w;
                s = waveReduceSum(s);
                float inv = 1.0f / fmaxf(sqrtf(s), 1e-12f);
                if (l == 0) inv_norm[r] = inv;
                facc[0] += v0.x * inv; facc[1] += v0.y * inv;
                facc[2] += v0.z * inv; facc[3] += v0.w * inv;
                facc[4] += v1.x * inv; facc[5] += v1.y * inv;
                facc[6] += v1.z * inv; facc[7] += v1.w * inv;
            }
        }
    }
    *reinterpret_cast<float4*>(&part[w][l * 8]) =
        make_float4(facc[0], facc[1], facc[2], facc[3]);
    *reinterpret_cast<float4*>(&part[w][l * 8 + 4]) =
        make_float4(facc[4], facc[5], facc[6], facc[7]);
    if (l == 0) cnts[w] = cnt;
    __syncthreads();
    if (tid < 512) {
        float s = 0.f;
#pragma unroll
        for (int r = 0; r < 16; ++r) s += part[r][tid];
        csum_bf[(size_t)c * 512 + tid] = f2bf(s);
        red[tid] = s * s;
    }
    __syncthreads();
    for (int o = 256; o >= 1; o >>= 1) {
        if (tid < o) red[tid] += red[tid + o];
        __syncthreads();
    }
    if (tid == 0) {
        int ct = 0;
#pragma unroll
        for (int r = 0; r < 16; ++r) ct += cnts[r];
        counts[c] = ct;
        float nsq = red[0];
        normsq[c] = nsq;
        colscale[c] = wptr[0] / fmaxf(sqrtf(nsq), (float)ct * 1e-8f);
    }
}

// --- K2: GEMM (64 rows x 256 cols per block, 8 waves); A reg-staged from emb ---
#define NKT 8

__global__ __launch_bounds__(512) void k_gemm(
        const float* __restrict__ emb, const float* __restrict__ inv_norm,
        const unsigned short* __restrict__ csum_bf,
        const int* __restrict__ y, const float* __restrict__ colscale,
        const float* __restrict__ normsq, const int* __restrict__ counts,
        const float* __restrict__ wptr, const float* __restrict__ bptr,
        float* __restrict__ colpart, float* __restrict__ selfpart, int C) {
    __shared__ __align__(16) unsigned short As[2][8 * 512];     // 2 x 8 KB
    __shared__ __align__(16) unsigned short Bs[2][32 * 512];    // 2 x 32 KB
    __shared__ float colsum[256];
    __shared__ float selfred[8];

    const int tid = threadIdx.x;
    const int l = tid & 63;
    const int w = tid >> 6;
    const int bx = blockIdx.x;
    const int r0 = bx * 64;
    const int rsub = l >> 2;
    const int kcs = ((l & 3) ^ ((l >> 3) & 3)) * 8;   // swizzled k-chunk (elements)

    const int arow = r0 + (w & 3) * 16 + rsub;
    const float* srcA = emb + (size_t)arow * 512 + (w >> 2) * 32 + kcs;
    const float invA = inv_norm[arow];
    const unsigned short* srcB[4];
#pragma unroll
    for (int i = 0; i < 4; ++i) {
        int st = w * 4 + i;
        srcB[i] = csum_bf + (size_t)((st & 15) * 16 + rsub) * 512 + (st >> 4) * 32 + kcs;
    }
    const int fro = (l & 15) * 32 + (((l >> 4) ^ ((l >> 1) & 3)) * 8);

    f32x4 acc[4][2];
#pragma unroll
    for (int m = 0; m < 4; ++m)
#pragma unroll
        for (int n = 0; n < 2; ++n) acc[m][n] = (f32x4){0.f, 0.f, 0.f, 0.f};

    // prologue: stage kt=0
    {
        float4 a0 = *reinterpret_cast<const float4*>(srcA);
        float4 a1 = *reinterpret_cast<const float4*>(srcA + 4);
        US8 t;
        t.u[0] = f2bf(a0.x * invA); t.u[1] = f2bf(a0.y * invA);
        t.u[2] = f2bf(a0.z * invA); t.u[3] = f2bf(a0.w * invA);
        t.u[4] = f2bf(a1.x * invA); t.u[5] = f2bf(a1.y * invA);
        t.u[6] = f2bf(a1.z * invA); t.u[7] = f2bf(a1.w * invA);
        *reinterpret_cast<US8*>(&As[0][w * 512 + l * 8]) = t;
    }
#pragma unroll
    for (int i = 0; i < 4; ++i) gload_lds16(srcB[i], &Bs[0][(w * 4 + i) * 512]);
    __syncthreads();

    int cur = 0;
    for (int kt = 0; kt < NKT; ++kt) {
        float4 a0, a1;
        const bool hasNext = (kt + 1 < NKT);
        if (hasNext) {
            a0 = *reinterpret_cast<const float4*>(srcA + (kt + 1) * 64);      // issue early
            a1 = *reinterpret_cast<const float4*>(srcA + (kt + 1) * 64 + 4);
#pragma unroll
            for (int i = 0; i < 4; ++i)
                gload_lds16(srcB[i] + (kt + 1) * 64, &Bs[cur ^ 1][(w * 4 + i) * 512]);
        }
#pragma unroll
        for (int h = 0; h < 2; ++h) {
            bf16x8 af[4];
#pragma unroll
            for (int m = 0; m < 4; ++m)
                af[m] = *reinterpret_cast<const bf16x8*>(&As[cur][(h * 4 + m) * 512 + fro]);
#pragma unroll
            for (int n = 0; n < 2; ++n) {
                bf16x8 bv = *reinterpret_cast<const bf16x8*>(
                    &Bs[cur][(h * 16 + w * 2 + n) * 512 + fro]);
#pragma unroll
                for (int m = 0; m < 4; ++m)
                    acc[m][n] = __builtin_amdgcn_mfma_f32_16x16x32_bf16(af[m], bv, acc[m][n], 0, 0, 0);
            }
        }
        if (hasNext) {   // convert+write after compute (loads hid under MFMA phase)
            US8 t;
            t.u[0] = f2bf(a0.x * invA); t.u[1] = f2bf(a0.y * invA);
            t.u[2] = f2bf(a0.z * invA); t.u[3] = f2bf(a0.w * invA);
            t.u[4] = f2bf(a1.x * invA); t.u[5] = f2bf(a1.y * invA);
            t.u[6] = f2bf(a1.z * invA); t.u[7] = f2bf(a1.w * invA);
            *reinterpret_cast<US8*>(&As[cur ^ 1][w * 512 + l * 8]) = t;
        }
        __syncthreads();
        cur ^= 1;
    }

    // epilogue: C/D layout col=lane&15, row=(lane>>4)*4+j; wave w -> cols w*32..+31
    float bv = bptr[0], wv = wptr[0];
    int lcol = l & 15, lrow4 = (l >> 4) * 4;
    float cs[2], nsq[2], cm1[2]; int cls[2];
#pragma unroll
    for (int n = 0; n < 2; ++n) {
        int c = w * 32 + n * 16 + lcol;
        cls[n] = c; cs[n] = colscale[c]; nsq[n] = normsq[c];
        cm1[n] = (float)(counts[c] - 1);
    }
    float colacc[2] = {0.f, 0.f};
    float selfacc = 0.f;
#pragma unroll
    for (int m = 0; m < 4; ++m) {
#pragma unroll
        for (int j = 0; j < 4; ++j) {
            int row = r0 + m * 16 + lrow4 + j;
            int yc = y[row];
#pragma unroll
            for (int n = 0; n < 2; ++n) {
                float dot = acc[m][n][j];
                float logit;
                if (yc == cls[n]) {
                    float un2 = fmaxf(nsq[n] - 2.f * dot + 1.f, 0.f);
                    float denom = fmaxf(sqrtf(un2), cm1[n] * 1e-8f);
                    logit = wv * (dot - 1.f) / denom + bv;
                    selfacc += logit;
                } else {
                    logit = dot * cs[n] + bv;
                }
                colacc[n] += __expf(logit);
            }
        }
    }
#pragma unroll
    for (int n = 0; n < 2; ++n) {
        float v = colacc[n];
        v += __shfl_xor(v, 16, 64);
        v += __shfl_xor(v, 32, 64);
        colacc[n] = v;
    }
    selfacc = waveReduceSum(selfacc);
    if (l < 16) {
#pragma unroll
        for (int n = 0; n < 2; ++n) colsum[w * 32 + n * 16 + l] = colacc[n];
    }
    if (l == 0) selfred[w] = selfacc;
    __syncthreads();
    if (tid < 256)
        colpart[(size_t)bx * 256 + tid] = colsum[tid];
    if (tid == 0)
        selfpart[bx] = selfred[0] + selfred[1] + selfred[2] + selfred[3]
                     + selfred[4] + selfred[5] + selfred[6] + selfred[7];
}

// --- K3: per-class reduce, one concurrent scattered load per thread ---
__global__ __launch_bounds__(256) void k_colreduce(
        const float* __restrict__ colpart, const int* __restrict__ counts,
        float* __restrict__ contrib, int nbx, int C) {
    __shared__ float red[256];
    int c = blockIdx.x, tid = threadIdx.x;
    float s = 0.f;
    for (int i = tid; i < nbx; i += 256)       // nbx=256: exactly one load/thread
        s += colpart[(size_t)i * C + c];
    red[tid] = s;
    __syncthreads();
    for (int o = 128; o >= 1; o >>= 1) {
        if (tid < o) red[tid] += red[tid + o];
        __syncthreads();
    }
    if (tid == 0) contrib[c] = (float)counts[c] * logf(red[0]);
}

// --- K4: finalize: sum contribs minus self partials ---
__global__ __launch_bounds__(256) void k_final(
        const float* __restrict__ contrib, const float* __restrict__ selfpart,
        float* __restrict__ out, int nbx, int C) {
    __shared__ float lds[256];
    int tid = threadIdx.x;
    float v = (tid < C) ? contrib[tid] : 0.f;
    for (int i = tid; i < nbx; i += 256) v -= selfpart[i];
    lds[tid] = v;
    __syncthreads();
    for (int o = 128; o >= 1; o >>= 1) {
        if (tid < o) lds[tid] += lds[tid + o];
        __syncthreads();
    }
    if (tid == 0) out[0] = lds[0];
}

extern "C" void kernel_launch(void* const* d_in, const int* in_sizes, int n_in,
                              void* d_out, int out_size, void* d_ws, size_t ws_size,
                              hipStream_t stream) {
    const float* emb  = (const float*)d_in[0];
    const int*   y    = (const int*)d_in[1];
    const float* wptr = (const float*)d_in[2];
    const float* bptr = (const float*)d_in[3];
    float* out = (float*)d_out;
    int N = in_sizes[1];                      // 16384
    const int C = 256;
    int nbx = N / 64;                         // 256

    float* inv_norm = (float*)d_ws;                                  // N
    unsigned short* csum_bf = (unsigned short*)(inv_norm + N);       // C*512 bf16
    float* colpart  = (float*)(csum_bf + (size_t)C * 512);           // nbx*C
    float* selfpart = colpart + (size_t)nbx * C;                     // nbx
    float* normsq   = selfpart + nbx;                                // C
    float* colscale = normsq + C;                                    // C
    int*   counts   = (int*)(colscale + C);                          // C
    float* contrib  = (float*)(counts + C);                          // C

    k_centroid <<<C, 1024, 0, stream>>>(emb, y, wptr, inv_norm, csum_bf, normsq,
                                        colscale, counts, N);
    k_gemm     <<<nbx, 512, 0, stream>>>(emb, inv_norm, csum_bf, y, colscale, normsq,
                                         counts, wptr, bptr, colpart, selfpart, C);
    k_colreduce<<<C, 256, 0, stream>>>(colpart, counts, contrib, nbx, C);
    k_final    <<<1, 256, 0, stream>>>(contrib, selfpart, out, nbx, C);
}